// Round 3
// baseline (94.337 us; speedup 1.0000x reference)
//
#include <hip/hip_runtime.h>

#define GG 256
#define PP 512
#define FF 4
#define KK 6
#define NN (GG*PP)

// sorted-desc cascade insert of key kv into B[0..5] (B[0] = worst/largest).
// caller guarantees kv < B[0]. strict < ; keys unique (index in low bits).
__device__ __forceinline__ void cas6(uint64_t (&B)[6], uint64_t kv)
{
    bool c1 = kv < B[1]; bool c2 = kv < B[2]; bool c3 = kv < B[3];
    bool c4 = kv < B[4]; bool c5 = kv < B[5];
    B[0] = c1 ? B[1] : kv;
    B[1] = c2 ? B[2] : (c1 ? kv : B[1]);
    B[2] = c3 ? B[3] : (c2 ? kv : B[2]);
    B[3] = c4 ? B[4] : (c3 ? kv : B[3]);
    B[4] = c5 ? B[5] : (c4 ? kv : B[4]);
    B[5] = c5 ? kv : B[5];
}

__global__ __launch_bounds__(512) void prep_kernel(
    const float* __restrict__ x,
    const float* __restrict__ pre_W1, const float* __restrict__ pre_b1, const float* __restrict__ pre_a1,
    const float* __restrict__ pre_W2, const float* __restrict__ pre_b2, const float* __restrict__ pre_a2,
    float4* __restrict__ xm2,       // [N] = -2*x
    float* __restrict__ sqv,        // [N] = |x|^2
    float* __restrict__ stats_raw)  // [8] atomic accum (0..3 sum, 4..7 sumsq)
{
    __shared__ float wred[8][8];
    const int g = blockIdx.x, t = threadIdx.x;
    const int gp = g*PP + t;

    float4 xt = ((const float4*)x)[gp];
    xm2[gp] = make_float4(-2.0f*xt.x, -2.0f*xt.y, -2.0f*xt.z, -2.0f*xt.w);
    sqv[gp] = xt.x*xt.x + xt.y*xt.y + xt.z*xt.z + xt.w*xt.w;

    // fused pre_nn (for BN stats only)
    float h1[FF], h2[FF];
#pragma unroll
    for (int fo=0;fo<FF;fo++){
        float m = xt.x*pre_W1[0*FF+fo] + xt.y*pre_W1[1*FF+fo]
                + xt.z*pre_W1[2*FF+fo] + xt.w*pre_W1[3*FF+fo] + pre_b1[fo];
        h1[fo] = m >= 0.0f ? m : pre_a1[fo]*m;
    }
#pragma unroll
    for (int fo=0;fo<FF;fo++){
        float m = h1[0]*pre_W2[0*FF+fo] + h1[1]*pre_W2[1*FF+fo]
                + h1[2]*pre_W2[2*FF+fo] + h1[3]*pre_W2[3*FF+fo] + pre_b2[fo];
        h2[fo] = m >= 0.0f ? m : pre_a2[fo]*m;
    }

    float v[8];
#pragma unroll
    for (int f=0;f<4;f++){ v[f]=h2[f]; v[4+f]=h2[f]*h2[f]; }
#pragma unroll
    for (int off=32; off; off>>=1){
#pragma unroll
        for (int f=0;f<8;f++) v[f] += __shfl_down(v[f], off);
    }
    int w = t>>6;
    if ((t&63)==0){
#pragma unroll
        for (int f=0;f<8;f++) wred[w][f]=v[f];
    }
    __syncthreads();
    if (t < 8){
        float a=0;
#pragma unroll
        for (int w2=0;w2<8;w2++) a += wred[w2][t];
        atomicAdd(&stats_raw[t], a);
    }
}

__global__ __launch_bounds__(512) void scan_kernel(
    const float* __restrict__ x,
    const float4* __restrict__ xm2,
    const float* __restrict__ sqv,
    int* __restrict__ knn_idx)      // [K][N] local neighbor idx (0..511)
{
    __shared__ unsigned ldsHi[4][6][128];
    __shared__ unsigned ldsLo[4][6][128];
    const int t = threadIdx.x;
    const int bid = blockIdx.x;
    const int g = bid >> 2, quarter = bid & 3;
    const int gbase = g * PP;
    const int w = t >> 6, lane = t & 63;
    const int s = w & 3;                 // scanner = candidate quarter
    const int lt = (w >> 2)*64 + lane;   // local target 0..127
    const int p = quarter*128 + lt;      // target node 0..511

    const int su = __builtin_amdgcn_readfirstlane(s);   // wave-uniform
    const float4* __restrict__ cm = xm2 + gbase + su*128;
    const float*  __restrict__ cs = sqv + gbase + su*128;
    const int qbase = su*128;

    float4 xp = ((const float4*)x)[gbase + p];

    uint64_t bd[6];
#pragma unroll
    for (int j=0;j<6;j++) bd[j] = ~0ull;
    uint64_t pk = 0; bool hp = false;

    for (int i=0;i<128;i++){
        float4 m = cm[i];
        float sqq = cs[i];
        // shifted distance: |x_q|^2 - 2 x_q . x_p  (constant |x_p|^2 offset dropped)
        float acc = fmaf(m.w, xp.w, fmaf(m.z, xp.z, fmaf(m.y, xp.y, m.x*xp.x))) + sqq;
        int bb = __float_as_int(acc);
        unsigned uu = (unsigned)bb ^ (unsigned)((bb>>31) | (int)0x80000000);
        uint64_t key = ((uint64_t)uu << 32) | (unsigned)(qbase + i);
        bool pass = (key < bd[0]) && (qbase + i != p);
        if (__any(pass && hp)){
            if (hp && pk < bd[0]) cas6(bd, pk);
            hp = false;
        }
        if (pass){ pk = key; hp = true; }
    }
    if (hp && pk < bd[0]) cas6(bd, pk);

#pragma unroll
    for (int j=0;j<6;j++){
        ldsHi[s][j][lt] = (unsigned)(bd[j] >> 32);
        ldsLo[s][j][lt] = (unsigned)(bd[j] & 0xFFFFFFFFull);
    }
    __syncthreads();

    if (t < 128){
        uint64_t best[6];
#pragma unroll
        for (int j=0;j<6;j++) best[j] = ~0ull;
#pragma unroll
        for (int s2=0;s2<4;s2++){
#pragma unroll
            for (int j=0;j<6;j++){
                uint64_t key = ((uint64_t)ldsHi[s2][j][t] << 32) | ldsLo[s2][j][t];
                if (key < best[0]) cas6(best, key);
            }
        }
        const int pp = quarter*128 + t;
#pragma unroll
        for (int j=0;j<6;j++)
            knn_idx[j*NN + gbase + pp] = (int)(best[j] & 0xFFFFFFFFull);
    }
}

__global__ __launch_bounds__(512) void graph_kernel(
    const float* __restrict__ x,
    const int* __restrict__ knn_idx,
    const float* __restrict__ stats_raw,
    const float* __restrict__ pre_W1, const float* __restrict__ pre_b1, const float* __restrict__ pre_a1,
    const float* __restrict__ pre_W2, const float* __restrict__ pre_b2, const float* __restrict__ pre_a2,
    const float* __restrict__ bn_g, const float* __restrict__ bn_b,
    const float* __restrict__ act_a,
    const float* __restrict__ conv_Wm, const float* __restrict__ conv_bm,
    const float* __restrict__ hlv_W1, const float* __restrict__ hlv_b1,
    const float* __restrict__ hlv_W2, const float* __restrict__ hlv_b2,
    float* __restrict__ out)
{
    __shared__ float4 hbuf[PP];
    __shared__ float wred[8][4];
    __shared__ float pooled[20];
    __shared__ float stats[8];   // 0..3 mu, 4..7 invstd
    __shared__ float hid[20];
    const int g = blockIdx.x, p = threadIdx.x;
    const int gp = g*PP + p;

    if (p < 4){
        float s0 = stats_raw[p], s1 = stats_raw[4+p];
        float mu  = s0 * (1.0f/NN);
        float var = s1 * (1.0f/NN) - mu*mu;
        stats[p]   = mu;
        stats[4+p] = 1.0f / sqrtf(var + 1e-5f);
    }

    // recompute pre_nn for this node (cheap; avoids a 2MB h2 buffer)
    float4 xt = ((const float4*)x)[gp];
    float h1[FF], h2[FF];
#pragma unroll
    for (int fo=0;fo<FF;fo++){
        float m = xt.x*pre_W1[0*FF+fo] + xt.y*pre_W1[1*FF+fo]
                + xt.z*pre_W1[2*FF+fo] + xt.w*pre_W1[3*FF+fo] + pre_b1[fo];
        h1[fo] = m >= 0.0f ? m : pre_a1[fo]*m;
    }
#pragma unroll
    for (int fo=0;fo<FF;fo++){
        float m = h1[0]*pre_W2[0*FF+fo] + h1[1]*pre_W2[1*FF+fo]
                + h1[2]*pre_W2[2*FF+fo] + h1[3]*pre_W2[3*FF+fo] + pre_b2[fo];
        h2[fo] = m >= 0.0f ? m : pre_a2[fo]*m;
    }
    __syncthreads();   // stats ready

    float hp[4];
#pragma unroll
    for (int f=0;f<4;f++)
        hp[f] = (h2[f] - stats[f]) * stats[4+f] * bn_g[f] + bn_b[f];
    hbuf[p] = make_float4(hp[0],hp[1],hp[2],hp[3]);
    int nb[KK];
#pragma unroll
    for (int j=0;j<KK;j++) nb[j] = knn_idx[j*NN + gp];

    auto block_accum = [&](const float* h, int slice){
        float v0=h[0], v1=h[1], v2=h[2], v3=h[3];
#pragma unroll
        for (int off=32; off; off>>=1){
            v0 += __shfl_down(v0,off); v1 += __shfl_down(v1,off);
            v2 += __shfl_down(v2,off); v3 += __shfl_down(v3,off);
        }
        int w = p>>6;
        if ((p&63)==0){ wred[w][0]=v0; wred[w][1]=v1; wred[w][2]=v2; wred[w][3]=v3; }
        __syncthreads();
        if (p < 4){
            float a=0;
#pragma unroll
            for (int w2=0;w2<8;w2++) a += wred[w2][p];
            pooled[slice*4+p] = a;
        }
        __syncthreads();
    };

    block_accum(hp, 0);   // syncs also publish hbuf before layer-0 gathers

#pragma unroll 1
    for (int L=0; L<4; L++){
        float4 sm = make_float4(0.f,0.f,0.f,0.f);
#pragma unroll
        for (int j=0;j<KK;j++){
            float4 hn = hbuf[nb[j]];
            sm.x+=hn.x; sm.y+=hn.y; sm.z+=hn.z; sm.w+=hn.w;
        }
        const float* W  = conv_Wm + L*16;
        const float* bm = conv_bm + L*4;
        float nh[4];
#pragma unroll
        for (int fo=0;fo<4;fo++){
            float m = sm.x*W[0*4+fo] + sm.y*W[1*4+fo] + sm.z*W[2*4+fo] + sm.w*W[3*4+fo]
                    + 6.0f*bm[fo] + hp[fo];
            float a = act_a[fo];
            nh[fo] = m >= 0.0f ? m : a*m;
        }
        __syncthreads();   // all gathers of old hbuf complete
        hbuf[p] = make_float4(nh[0],nh[1],nh[2],nh[3]);
#pragma unroll
        for (int f=0;f<4;f++) hp[f]=nh[f];
        block_accum(hp, L+1);  // internal sync publishes new hbuf
    }

    // head MLP: relu(pooled @ W1 + b1) @ W2 + b2
    if (p < 20){
        float acc = hlv_b1[p];
#pragma unroll 1
        for (int k2=0;k2<20;k2++) acc += pooled[k2]*hlv_W1[k2*20+p];
        hid[p] = acc > 0.0f ? acc : 0.0f;
    }
    __syncthreads();
    if (p == 0){
        float o = hlv_b2[0];
#pragma unroll 1
        for (int j=0;j<20;j++) o += hid[j]*hlv_W2[j];
        out[g] = o;
    }
}

extern "C" void kernel_launch(void* const* d_in, const int* in_sizes, int n_in,
                              void* d_out, int out_size, void* d_ws, size_t ws_size,
                              hipStream_t stream)
{
    const float* x      = (const float*)d_in[0];
    const float* pre_W1 = (const float*)d_in[2];
    const float* pre_b1 = (const float*)d_in[3];
    const float* pre_a1 = (const float*)d_in[4];
    const float* pre_W2 = (const float*)d_in[5];
    const float* pre_b2 = (const float*)d_in[6];
    const float* pre_a2 = (const float*)d_in[7];
    const float* bn_g   = (const float*)d_in[8];
    const float* bn_b   = (const float*)d_in[9];
    const float* act_a  = (const float*)d_in[10];
    const float* conv_Wm= (const float*)d_in[11];
    const float* conv_bm= (const float*)d_in[12];
    const float* hlv_W1 = (const float*)d_in[13];
    const float* hlv_b1 = (const float*)d_in[14];
    const float* hlv_W2 = (const float*)d_in[15];
    const float* hlv_b2 = (const float*)d_in[16];

    char* ws = (char*)d_ws;
    float4* xm2       = (float4*)ws;                                   // 2 MB
    float*  sqv       = (float*)(ws + (size_t)NN*sizeof(float4));      // 512 KB
    int*    knn       = (int*)(ws + (size_t)NN*20);                    // 3 MB
    float*  stats_raw = (float*)(ws + (size_t)NN*20 + (size_t)6*NN*sizeof(int)); // 32 B

    hipMemsetAsync(stats_raw, 0, 8*sizeof(float), stream);

    prep_kernel<<<GG, PP, 0, stream>>>(x, pre_W1,pre_b1,pre_a1, pre_W2,pre_b2,pre_a2,
                                       xm2, sqv, stats_raw);
    scan_kernel<<<GG*4, PP, 0, stream>>>(x, xm2, sqv, knn);
    graph_kernel<<<GG, PP, 0, stream>>>(x, knn, stats_raw,
                                        pre_W1,pre_b1,pre_a1, pre_W2,pre_b2,pre_a2,
                                        bn_g,bn_b, act_a, conv_Wm,conv_bm,
                                        hlv_W1,hlv_b1,hlv_W2,hlv_b2,
                                        (float*)d_out);
}

// Round 4
// 75.547 us; speedup vs baseline: 1.2487x; 1.2487x over previous
//
#include <hip/hip_runtime.h>

#define GG 256
#define PP 512
#define FF 4
#define KK 6
#define NN (GG*PP)

__device__ __forceinline__ unsigned umin_(unsigned a, unsigned b){ return a<b?a:b; }
__device__ __forceinline__ unsigned umax_(unsigned a, unsigned b){ return a>b?a:b; }

// branchless ascending-sorted 6-slot insert (S[5] = worst). med3 pattern.
#define INS6(S0,S1,S2,S3,S4,S5,m)                      \
    {                                                  \
        unsigned n0 = umin_(S0, m);                    \
        unsigned n1 = umin_(S1, umax_(m, S0));         \
        unsigned n2 = umin_(S2, umax_(m, S1));         \
        unsigned n3 = umin_(S3, umax_(m, S2));         \
        unsigned n4 = umin_(S4, umax_(m, S3));         \
        unsigned n5 = umin_(S5, umax_(m, S4));         \
        S0=n0; S1=n1; S2=n2; S3=n3; S4=n4; S5=n5;      \
    }

// u64 sorted-desc cascade (for rare tie-redo path)
__device__ __forceinline__ void cas6_u64(uint64_t (&B)[6], uint64_t kv)
{
    bool c1 = kv < B[1]; bool c2 = kv < B[2]; bool c3 = kv < B[3];
    bool c4 = kv < B[4]; bool c5 = kv < B[5];
    B[0] = c1 ? B[1] : kv;
    B[1] = c2 ? B[2] : (c1 ? kv : B[1]);
    B[2] = c3 ? B[3] : (c2 ? kv : B[2]);
    B[3] = c4 ? B[4] : (c3 ? kv : B[3]);
    B[4] = c5 ? B[5] : (c4 ? kv : B[4]);
    B[5] = c5 ? kv : B[5];
}

__global__ __launch_bounds__(512) void scan_kernel(
    const float* __restrict__ x,
    const float* __restrict__ pre_W1, const float* __restrict__ pre_b1, const float* __restrict__ pre_a1,
    const float* __restrict__ pre_W2, const float* __restrict__ pre_b2, const float* __restrict__ pre_a2,
    float* __restrict__ stats_raw,   // [8] atomic accum
    int* __restrict__ knn_idx)       // [K][N]
{
    __shared__ float4   xs[PP];          // raw x for this graph (8 KB)
    __shared__ unsigned lists[128][25];  // per-target 4x6 pass-1 results (padded)
    __shared__ unsigned Tval[128];
    __shared__ unsigned cnt[128];
    __shared__ float    wred[8][8];

    const int t = threadIdx.x;
    const int bid = blockIdx.x;
    const int g = bid >> 2, quarter = bid & 3;
    const int gbase = g * PP;
    const int w = t >> 6, lane = t & 63;
    const int s  = w & 3;                  // scanner quarter (wave-uniform)
    const int lt = (w >> 2)*64 + lane;     // local target 0..127
    const int p  = quarter*128 + lt;       // target node 0..511

    float4 xt = ((const float4*)x)[gbase + t];
    xs[t] = xt;

    // folded prep: BN stats over pre_nn(x), only on quarter-0 blocks
    if (quarter == 0){
        float h1[FF], h2[FF];
#pragma unroll
        for (int fo=0;fo<FF;fo++){
            float m = xt.x*pre_W1[0*FF+fo] + xt.y*pre_W1[1*FF+fo]
                    + xt.z*pre_W1[2*FF+fo] + xt.w*pre_W1[3*FF+fo] + pre_b1[fo];
            h1[fo] = m >= 0.0f ? m : pre_a1[fo]*m;
        }
#pragma unroll
        for (int fo=0;fo<FF;fo++){
            float m = h1[0]*pre_W2[0*FF+fo] + h1[1]*pre_W2[1*FF+fo]
                    + h1[2]*pre_W2[2*FF+fo] + h1[3]*pre_W2[3*FF+fo] + pre_b2[fo];
            h2[fo] = m >= 0.0f ? m : pre_a2[fo]*m;
        }
        float v[8];
#pragma unroll
        for (int f=0;f<4;f++){ v[f]=h2[f]; v[4+f]=h2[f]*h2[f]; }
#pragma unroll
        for (int off=32; off; off>>=1){
#pragma unroll
            for (int f=0;f<8;f++) v[f] += __shfl_down(v[f], off);
        }
        if ((t&63)==0){
#pragma unroll
            for (int f=0;f<8;f++) wred[w][f]=v[f];
        }
    }
    __syncthreads();
    if (quarter == 0 && t < 8){
        float a=0;
#pragma unroll
        for (int w2=0;w2<8;w2++) a += wred[w2][t];
        atomicAdd(&stats_raw[t], a);
    }

    const int su = __builtin_amdgcn_readfirstlane(s);
    const int qb = su*128;
    float4 xp = xs[p];

    // ---- pass 1: 6 smallest DISTANCES (values only) over this quarter ----
    unsigned S0=0xFFFFFFFFu,S1=0xFFFFFFFFu,S2=0xFFFFFFFFu,
             S3=0xFFFFFFFFu,S4=0xFFFFFFFFu,S5=0xFFFFFFFFu;
#pragma unroll 4
    for (int i=0;i<128;i++){
        float4 c = xs[qb+i];
        float d0=xp.x-c.x, d1=xp.y-c.y, d2=xp.z-c.z, d3=xp.w-c.w;
        float d = fmaf(d0,d0, fmaf(d1,d1, fmaf(d2,d2, d3*d3)));
        unsigned m = __float_as_uint(d);
        m = (qb+i == p) ? 0xFFFFFFFFu : m;
        INS6(S0,S1,S2,S3,S4,S5,m);
    }
    lists[lt][s*6+0]=S0; lists[lt][s*6+1]=S1; lists[lt][s*6+2]=S2;
    lists[lt][s*6+3]=S3; lists[lt][s*6+4]=S4; lists[lt][s*6+5]=S5;
    __syncthreads();

    // ---- merge: 6th smallest of the 24 candidates -> T ----
    if (t < 128){
        unsigned M0=0xFFFFFFFFu,M1=0xFFFFFFFFu,M2=0xFFFFFFFFu,
                 M3=0xFFFFFFFFu,M4=0xFFFFFFFFu,M5=0xFFFFFFFFu;
#pragma unroll
        for (int j=0;j<24;j++){
            unsigned m = lists[t][j];
            INS6(M0,M1,M2,M3,M4,M5,m);
        }
        Tval[t] = M5;
        cnt[t] = 0;
    }
    __syncthreads();

    // ---- pass 2: recover indices (d <= T), order-free ----
    const unsigned T = Tval[lt];
#pragma unroll 4
    for (int i=0;i<128;i++){
        float4 c = xs[qb+i];
        float d0=xp.x-c.x, d1=xp.y-c.y, d2=xp.z-c.z, d3=xp.w-c.w;
        float d = fmaf(d0,d0, fmaf(d1,d1, fmaf(d2,d2, d3*d3)));
        unsigned m = __float_as_uint(d);
        if (m <= T && (qb+i != p)){
            unsigned j = atomicAdd(&cnt[lt], 1u);
            if (j < 6) knn_idx[j*NN + gbase + p] = qb + i;
        }
    }
    __syncthreads();

    // ---- rare exact redo on distance ties spanning the rank-6 boundary ----
    if (t < 128 && cnt[t] > 6){
        const int pt = quarter*128 + t;
        float4 xq = xs[pt];
        uint64_t B[6];
#pragma unroll
        for (int j=0;j<6;j++) B[j] = ~0ull;
        for (int q=0;q<PP;q++){
            if (q == pt) continue;
            float4 c = xs[q];
            float d0=xq.x-c.x, d1=xq.y-c.y, d2=xq.z-c.z, d3=xq.w-c.w;
            float d = fmaf(d0,d0, fmaf(d1,d1, fmaf(d2,d2, d3*d3)));
            uint64_t key = ((uint64_t)__float_as_uint(d) << 32) | (unsigned)q;
            if (key < B[0]) cas6_u64(B, key);
        }
#pragma unroll
        for (int j=0;j<6;j++)
            knn_idx[j*NN + gbase + pt] = (int)(B[j] & 0xFFFFFFFFull);
    }
}

__global__ __launch_bounds__(512) void graph_kernel(
    const float* __restrict__ x,
    const int* __restrict__ knn_idx,
    const float* __restrict__ stats_raw,
    const float* __restrict__ pre_W1, const float* __restrict__ pre_b1, const float* __restrict__ pre_a1,
    const float* __restrict__ pre_W2, const float* __restrict__ pre_b2, const float* __restrict__ pre_a2,
    const float* __restrict__ bn_g, const float* __restrict__ bn_b,
    const float* __restrict__ act_a,
    const float* __restrict__ conv_Wm, const float* __restrict__ conv_bm,
    const float* __restrict__ hlv_W1, const float* __restrict__ hlv_b1,
    const float* __restrict__ hlv_W2, const float* __restrict__ hlv_b2,
    float* __restrict__ out)
{
    __shared__ float4 hbuf[PP];
    __shared__ float wred[8][4];
    __shared__ float pooled[20];
    __shared__ float stats[8];   // 0..3 mu, 4..7 invstd
    __shared__ float hid[20];
    const int g = blockIdx.x, p = threadIdx.x;
    const int gp = g*PP + p;

    if (p < 4){
        float s0 = stats_raw[p], s1 = stats_raw[4+p];
        float mu  = s0 * (1.0f/NN);
        float var = s1 * (1.0f/NN) - mu*mu;
        stats[p]   = mu;
        stats[4+p] = 1.0f / sqrtf(var + 1e-5f);
    }

    float4 xt = ((const float4*)x)[gp];
    float h1[FF], h2[FF];
#pragma unroll
    for (int fo=0;fo<FF;fo++){
        float m = xt.x*pre_W1[0*FF+fo] + xt.y*pre_W1[1*FF+fo]
                + xt.z*pre_W1[2*FF+fo] + xt.w*pre_W1[3*FF+fo] + pre_b1[fo];
        h1[fo] = m >= 0.0f ? m : pre_a1[fo]*m;
    }
#pragma unroll
    for (int fo=0;fo<FF;fo++){
        float m = h1[0]*pre_W2[0*FF+fo] + h1[1]*pre_W2[1*FF+fo]
                + h1[2]*pre_W2[2*FF+fo] + h1[3]*pre_W2[3*FF+fo] + pre_b2[fo];
        h2[fo] = m >= 0.0f ? m : pre_a2[fo]*m;
    }
    __syncthreads();   // stats ready

    float hp[4];
#pragma unroll
    for (int f=0;f<4;f++)
        hp[f] = (h2[f] - stats[f]) * stats[4+f] * bn_g[f] + bn_b[f];
    hbuf[p] = make_float4(hp[0],hp[1],hp[2],hp[3]);
    int nb[KK];
#pragma unroll
    for (int j=0;j<KK;j++) nb[j] = knn_idx[j*NN + gp];

    auto block_accum = [&](const float* h, int slice){
        float v0=h[0], v1=h[1], v2=h[2], v3=h[3];
#pragma unroll
        for (int off=32; off; off>>=1){
            v0 += __shfl_down(v0,off); v1 += __shfl_down(v1,off);
            v2 += __shfl_down(v2,off); v3 += __shfl_down(v3,off);
        }
        int w = p>>6;
        if ((p&63)==0){ wred[w][0]=v0; wred[w][1]=v1; wred[w][2]=v2; wred[w][3]=v3; }
        __syncthreads();
        if (p < 4){
            float a=0;
#pragma unroll
            for (int w2=0;w2<8;w2++) a += wred[w2][p];
            pooled[slice*4+p] = a;
        }
        __syncthreads();
    };

    block_accum(hp, 0);

#pragma unroll 1
    for (int L=0; L<4; L++){
        float4 sm = make_float4(0.f,0.f,0.f,0.f);
#pragma unroll
        for (int j=0;j<KK;j++){
            float4 hn = hbuf[nb[j]];
            sm.x+=hn.x; sm.y+=hn.y; sm.z+=hn.z; sm.w+=hn.w;
        }
        const float* W  = conv_Wm + L*16;
        const float* bm = conv_bm + L*4;
        float nh[4];
#pragma unroll
        for (int fo=0;fo<4;fo++){
            float m = sm.x*W[0*4+fo] + sm.y*W[1*4+fo] + sm.z*W[2*4+fo] + sm.w*W[3*4+fo]
                    + 6.0f*bm[fo] + hp[fo];
            float a = act_a[fo];
            nh[fo] = m >= 0.0f ? m : a*m;
        }
        __syncthreads();
        hbuf[p] = make_float4(nh[0],nh[1],nh[2],nh[3]);
#pragma unroll
        for (int f=0;f<4;f++) hp[f]=nh[f];
        block_accum(hp, L+1);
    }

    if (p < 20){
        float acc = hlv_b1[p];
#pragma unroll 1
        for (int k2=0;k2<20;k2++) acc += pooled[k2]*hlv_W1[k2*20+p];
        hid[p] = acc > 0.0f ? acc : 0.0f;
    }
    __syncthreads();
    if (p == 0){
        float o = hlv_b2[0];
#pragma unroll 1
        for (int j=0;j<20;j++) o += hid[j]*hlv_W2[j];
        out[g] = o;
    }
}

extern "C" void kernel_launch(void* const* d_in, const int* in_sizes, int n_in,
                              void* d_out, int out_size, void* d_ws, size_t ws_size,
                              hipStream_t stream)
{
    const float* x      = (const float*)d_in[0];
    const float* pre_W1 = (const float*)d_in[2];
    const float* pre_b1 = (const float*)d_in[3];
    const float* pre_a1 = (const float*)d_in[4];
    const float* pre_W2 = (const float*)d_in[5];
    const float* pre_b2 = (const float*)d_in[6];
    const float* pre_a2 = (const float*)d_in[7];
    const float* bn_g   = (const float*)d_in[8];
    const float* bn_b   = (const float*)d_in[9];
    const float* act_a  = (const float*)d_in[10];
    const float* conv_Wm= (const float*)d_in[11];
    const float* conv_bm= (const float*)d_in[12];
    const float* hlv_W1 = (const float*)d_in[13];
    const float* hlv_b1 = (const float*)d_in[14];
    const float* hlv_W2 = (const float*)d_in[15];
    const float* hlv_b2 = (const float*)d_in[16];

    char* ws = (char*)d_ws;
    int*   knn       = (int*)ws;                                  // 3 MB
    float* stats_raw = (float*)(ws + (size_t)6*NN*sizeof(int));   // 32 B

    hipMemsetAsync(stats_raw, 0, 8*sizeof(float), stream);

    scan_kernel<<<GG*4, PP, 0, stream>>>(x, pre_W1,pre_b1,pre_a1,
                                         pre_W2,pre_b2,pre_a2, stats_raw, knn);
    graph_kernel<<<GG, PP, 0, stream>>>(x, knn, stats_raw,
                                        pre_W1,pre_b1,pre_a1, pre_W2,pre_b2,pre_a2,
                                        bn_g,bn_b, act_a, conv_Wm,conv_bm,
                                        hlv_W1,hlv_b1,hlv_W2,hlv_b2,
                                        (float*)d_out);
}

// Round 5
// 63.884 us; speedup vs baseline: 1.4767x; 1.1826x over previous
//
#include <hip/hip_runtime.h>

#define GG 256
#define PP 512
#define FF 4
#define KK 6
#define NN (GG*PP)

__device__ __forceinline__ float finf(){ return __int_as_float(0x7f800000); }

// u64 sorted-desc cascade (rare tie-redo path). B[0] = worst of the 6.
__device__ __forceinline__ void cas6_u64(uint64_t (&B)[6], uint64_t kv)
{
    bool c1 = kv < B[1]; bool c2 = kv < B[2]; bool c3 = kv < B[3];
    bool c4 = kv < B[4]; bool c5 = kv < B[5];
    B[0] = c1 ? B[1] : kv;
    B[1] = c2 ? B[2] : (c1 ? kv : B[1]);
    B[2] = c3 ? B[3] : (c2 ? kv : B[2]);
    B[3] = c4 ? B[4] : (c3 ? kv : B[3]);
    B[4] = c5 ? B[5] : (c4 ? kv : B[4]);
    B[5] = c5 ? kv : B[5];
}

__global__ __launch_bounds__(512) void scan_kernel(
    const float* __restrict__ x,
    const float* __restrict__ pre_W1, const float* __restrict__ pre_b1, const float* __restrict__ pre_a1,
    const float* __restrict__ pre_W2, const float* __restrict__ pre_b2, const float* __restrict__ pre_a2,
    float* __restrict__ bn_part,     // [8][G]
    int* __restrict__ knn_idx)       // [K][N]
{
    __shared__ float4   xm2s[PP];        // -2*x            (8 KB)
    __shared__ float    sqs[PP];         // |x|^2           (2 KB)
    __shared__ float    lists[128][29];  // 4 scanners x 7  (14.5 KB, stride 29 coprime w/ 32)
    __shared__ float    Tv[128];
    __shared__ unsigned cnt[128];
    __shared__ float    wred[8][8];

    const int t = threadIdx.x;
    const int bid = blockIdx.x;
    const int g = bid >> 2, quarter = bid & 3;
    const int gbase = g * PP;
    const int w = t >> 6, lane = t & 63;
    const int s  = w & 3;                  // scanner quarter (wave-uniform)
    const int lt = (w >> 2)*64 + lane;     // local target 0..127
    const int p  = quarter*128 + lt;       // target node 0..511

    float4 xt = ((const float4*)x)[gbase + t];
    xm2s[t] = make_float4(-2.0f*xt.x, -2.0f*xt.y, -2.0f*xt.z, -2.0f*xt.w);
    sqs[t]  = xt.x*xt.x + xt.y*xt.y + xt.z*xt.z + xt.w*xt.w;

    // BN stats over pre_nn(x) — quarter-0 blocks only
    if (quarter == 0){
        float h1[FF], h2[FF];
#pragma unroll
        for (int fo=0;fo<FF;fo++){
            float m = xt.x*pre_W1[0*FF+fo] + xt.y*pre_W1[1*FF+fo]
                    + xt.z*pre_W1[2*FF+fo] + xt.w*pre_W1[3*FF+fo] + pre_b1[fo];
            h1[fo] = m >= 0.0f ? m : pre_a1[fo]*m;
        }
#pragma unroll
        for (int fo=0;fo<FF;fo++){
            float m = h1[0]*pre_W2[0*FF+fo] + h1[1]*pre_W2[1*FF+fo]
                    + h1[2]*pre_W2[2*FF+fo] + h1[3]*pre_W2[3*FF+fo] + pre_b2[fo];
            h2[fo] = m >= 0.0f ? m : pre_a2[fo]*m;
        }
        float v[8];
#pragma unroll
        for (int f=0;f<4;f++){ v[f]=h2[f]; v[4+f]=h2[f]*h2[f]; }
#pragma unroll
        for (int off=32; off; off>>=1){
#pragma unroll
            for (int f=0;f<8;f++) v[f] += __shfl_down(v[f], off);
        }
        if ((t&63)==0){
#pragma unroll
            for (int f=0;f<8;f++) wred[w][f]=v[f];
        }
    }
    __syncthreads();          // publishes xm2s/sqs AND wred
    if (quarter == 0 && t < 8){
        float a=0;
#pragma unroll
        for (int w2=0;w2<8;w2++) a += wred[w2][t];
        bn_part[t*GG + g] = a;
    }

    const int su = __builtin_amdgcn_readfirstlane(s);
    const int qb = su*128;

    // target coords: xp = -0.5 * (-2*xp)  (exact)
    float4 xm = xm2s[p];
    float4 xp = make_float4(-0.5f*xm.x, -0.5f*xm.y, -0.5f*xm.z, -0.5f*xm.w);

    // ---- pass 1: 7 smallest shifted distances over this quarter, pair-merged ----
    // shifted d = |q|^2 - 2 q.p ; self = -|p|^2 is the strict minimum -> no self test.
    const float INF = finf();
    float A0=INF,A1=INF,A2=INF,A3=INF,A4=INF,A5=INF,A6=INF;
    uint64_t mask = 0;      // pair j -> bit (63-j): "pair may hold a final neighbor"

#pragma unroll 16
    for (int j=0;j<64;j++){
        float4 a = xm2s[qb + 2*j];
        float4 b = xm2s[qb + 2*j + 1];
        float da = fmaf(a.x,xp.x, fmaf(a.y,xp.y, fmaf(a.z,xp.z, fmaf(a.w,xp.w, sqs[qb+2*j]))));
        float db = fmaf(b.x,xp.x, fmaf(b.y,xp.y, fmaf(b.z,xp.z, fmaf(b.w,xp.w, sqs[qb+2*j+1]))));
        float b0 = fminf(da,db), b1 = fmaxf(da,db);
        mask = (mask << 1) | (uint64_t)(b0 <= A6 ? 1u : 0u);
        // merge sorted pair into sorted-7 (keep 7 smallest of 9)
        float x0=fmaxf(A0,b0), x1=fmaxf(A1,b0), x2=fmaxf(A2,b0),
              x3=fmaxf(A3,b0), x4=fmaxf(A4,b0), x5=fmaxf(A5,b0);
        float y0=fmaxf(A0,b1), y1=fmaxf(A1,b1), y2=fmaxf(A2,b1),
              y3=fmaxf(A3,b1), y4=fmaxf(A4,b1);
        float C0 = fminf(A0, b0);
        float C1 = fminf(fminf(A1, x0), b1);
        float C2 = fminf(fminf(A2, x1), y0);
        float C3 = fminf(fminf(A3, x2), y1);
        float C4 = fminf(fminf(A4, x3), y2);
        float C5 = fminf(fminf(A5, x4), y3);
        float C6 = fminf(fminf(A6, x5), y4);
        A0=C0; A1=C1; A2=C2; A3=C3; A4=C4; A5=C5; A6=C6;
    }

    lists[lt][s*7+0]=A0; lists[lt][s*7+1]=A1; lists[lt][s*7+2]=A2;
    lists[lt][s*7+3]=A3; lists[lt][s*7+4]=A4; lists[lt][s*7+5]=A5;
    lists[lt][s*7+6]=A6;
    __syncthreads();

    // ---- merge 4x7 -> T = 7th smallest incl. self (= 6th excl. self) ----
    if (t < 128){
        float M0=INF,M1=INF,M2=INF,M3=INF,M4=INF,M5=INF,M6=INF;
#pragma unroll
        for (int j=0;j<28;j++){
            float v = lists[t][j];
            float n0=fminf(M0,v);
            float n1=fminf(M1,fmaxf(v,M0));
            float n2=fminf(M2,fmaxf(v,M1));
            float n3=fminf(M3,fmaxf(v,M2));
            float n4=fminf(M4,fmaxf(v,M3));
            float n5=fminf(M5,fmaxf(v,M4));
            float n6=fminf(M6,fmaxf(v,M5));
            M0=n0;M1=n1;M2=n2;M3=n3;M4=n4;M5=n5;M6=n6;
        }
        Tv[t] = M6;
        cnt[t] = 0;
    }
    __syncthreads();

    // ---- recovery: walk flagged pairs only (~27 of 64), d<=T & q!=p -> emit ----
    {
        const float T = Tv[lt];
        uint64_t m = mask;
        while (__ballot(m != 0)){
            if (m){
                int k = __builtin_ctzll(m);
                m &= m - 1;
                int pj = 63 - k;
                int q0 = qb + 2*pj;
                float4 a = xm2s[q0];
                float4 b = xm2s[q0+1];
                float da = fmaf(a.x,xp.x, fmaf(a.y,xp.y, fmaf(a.z,xp.z, fmaf(a.w,xp.w, sqs[q0]))));
                float db = fmaf(b.x,xp.x, fmaf(b.y,xp.y, fmaf(b.z,xp.z, fmaf(b.w,xp.w, sqs[q0+1]))));
                if (da <= T && q0 != p){
                    unsigned jj = atomicAdd(&cnt[lt], 1u);
                    if (jj < 6) knn_idx[jj*NN + gbase + p] = q0;
                }
                if (db <= T && (q0+1) != p){
                    unsigned jj = atomicAdd(&cnt[lt], 1u);
                    if (jj < 6) knn_idx[jj*NN + gbase + p] = q0 + 1;
                }
            }
        }
    }
    __syncthreads();

    // ---- rare exact redo on boundary ties (cnt > 6) ----
    if (t < 128 && cnt[t] > 6){
        const int pt = quarter*128 + t;
        float4 xmq = xm2s[pt];
        float4 xq = make_float4(-0.5f*xmq.x, -0.5f*xmq.y, -0.5f*xmq.z, -0.5f*xmq.w);
        uint64_t B[6];
#pragma unroll
        for (int j=0;j<6;j++) B[j] = ~0ull;
        for (int q=0;q<PP;q++){
            if (q == pt) continue;
            float4 a = xm2s[q];
            float d = fmaf(a.x,xq.x, fmaf(a.y,xq.y, fmaf(a.z,xq.z, fmaf(a.w,xq.w, sqs[q]))));
            int bb = __float_as_int(d);
            unsigned uu = (bb >= 0) ? ((unsigned)bb ^ 0x80000000u) : (unsigned)(~bb);
            uint64_t key = ((uint64_t)uu << 32) | (unsigned)q;
            if (key < B[0]) cas6_u64(B, key);
        }
#pragma unroll
        for (int j=0;j<6;j++)
            knn_idx[j*NN + gbase + pt] = (int)(B[j] & 0xFFFFFFFFull);
    }
}

__global__ __launch_bounds__(512) void graph_kernel(
    const float* __restrict__ x,
    const int* __restrict__ knn_idx,
    const float* __restrict__ bn_part,
    const float* __restrict__ pre_W1, const float* __restrict__ pre_b1, const float* __restrict__ pre_a1,
    const float* __restrict__ pre_W2, const float* __restrict__ pre_b2, const float* __restrict__ pre_a2,
    const float* __restrict__ bn_g, const float* __restrict__ bn_b,
    const float* __restrict__ act_a,
    const float* __restrict__ conv_Wm, const float* __restrict__ conv_bm,
    const float* __restrict__ hlv_W1, const float* __restrict__ hlv_b1,
    const float* __restrict__ hlv_W2, const float* __restrict__ hlv_b2,
    float* __restrict__ out)
{
    __shared__ float4 hbuf[PP];
    __shared__ float wred[8][4];
    __shared__ float pooled[20];
    __shared__ float stats[8];   // 0..3 mu, 4..7 invstd
    __shared__ float hid[20];
    const int g = blockIdx.x, p = threadIdx.x;
    const int gp = g*PP + p;

    // global BN stat reduction (2KB, L2-hot)
    if (p < 64){
        int vv = p>>3, j = p&7;
        float acc = 0.0f;
        for (int i=j;i<GG;i+=8) acc += bn_part[vv*GG + i];
        acc += __shfl_xor(acc,1); acc += __shfl_xor(acc,2); acc += __shfl_xor(acc,4);
        if (j==0) stats[vv] = acc;
    }
    __syncthreads();
    if (p < 4){
        float mu  = stats[p]   * (1.0f/NN);
        float var = stats[4+p] * (1.0f/NN) - mu*mu;
        stats[p]   = mu;
        stats[4+p] = 1.0f / sqrtf(var + 1e-5f);
    }

    float4 xt = ((const float4*)x)[gp];
    float h1[FF], h2[FF];
#pragma unroll
    for (int fo=0;fo<FF;fo++){
        float m = xt.x*pre_W1[0*FF+fo] + xt.y*pre_W1[1*FF+fo]
                + xt.z*pre_W1[2*FF+fo] + xt.w*pre_W1[3*FF+fo] + pre_b1[fo];
        h1[fo] = m >= 0.0f ? m : pre_a1[fo]*m;
    }
#pragma unroll
    for (int fo=0;fo<FF;fo++){
        float m = h1[0]*pre_W2[0*FF+fo] + h1[1]*pre_W2[1*FF+fo]
                + h1[2]*pre_W2[2*FF+fo] + h1[3]*pre_W2[3*FF+fo] + pre_b2[fo];
        h2[fo] = m >= 0.0f ? m : pre_a2[fo]*m;
    }
    __syncthreads();   // stats ready

    float hp[4];
#pragma unroll
    for (int f=0;f<4;f++)
        hp[f] = (h2[f] - stats[f]) * stats[4+f] * bn_g[f] + bn_b[f];
    hbuf[p] = make_float4(hp[0],hp[1],hp[2],hp[3]);
    int nb[KK];
#pragma unroll
    for (int j=0;j<KK;j++) nb[j] = knn_idx[j*NN + gp];

    auto block_accum = [&](const float* h, int slice){
        float v0=h[0], v1=h[1], v2=h[2], v3=h[3];
#pragma unroll
        for (int off=32; off; off>>=1){
            v0 += __shfl_down(v0,off); v1 += __shfl_down(v1,off);
            v2 += __shfl_down(v2,off); v3 += __shfl_down(v3,off);
        }
        int w = p>>6;
        if ((p&63)==0){ wred[w][0]=v0; wred[w][1]=v1; wred[w][2]=v2; wred[w][3]=v3; }
        __syncthreads();
        if (p < 4){
            float a=0;
#pragma unroll
            for (int w2=0;w2<8;w2++) a += wred[w2][p];
            pooled[slice*4+p] = a;
        }
        __syncthreads();
    };

    block_accum(hp, 0);

#pragma unroll 1
    for (int L=0; L<4; L++){
        float4 sm = make_float4(0.f,0.f,0.f,0.f);
#pragma unroll
        for (int j=0;j<KK;j++){
            float4 hn = hbuf[nb[j]];
            sm.x+=hn.x; sm.y+=hn.y; sm.z+=hn.z; sm.w+=hn.w;
        }
        const float* W  = conv_Wm + L*16;
        const float* bm = conv_bm + L*4;
        float nh[4];
#pragma unroll
        for (int fo=0;fo<4;fo++){
            float m = sm.x*W[0*4+fo] + sm.y*W[1*4+fo] + sm.z*W[2*4+fo] + sm.w*W[3*4+fo]
                    + 6.0f*bm[fo] + hp[fo];
            float a = act_a[fo];
            nh[fo] = m >= 0.0f ? m : a*m;
        }
        __syncthreads();
        hbuf[p] = make_float4(nh[0],nh[1],nh[2],nh[3]);
#pragma unroll
        for (int f=0;f<4;f++) hp[f]=nh[f];
        block_accum(hp, L+1);
    }

    if (p < 20){
        float acc = hlv_b1[p];
#pragma unroll 1
        for (int k2=0;k2<20;k2++) acc += pooled[k2]*hlv_W1[k2*20+p];
        hid[p] = acc > 0.0f ? acc : 0.0f;
    }
    __syncthreads();
    if (p == 0){
        float o = hlv_b2[0];
#pragma unroll 1
        for (int j=0;j<20;j++) o += hid[j]*hlv_W2[j];
        out[g] = o;
    }
}

extern "C" void kernel_launch(void* const* d_in, const int* in_sizes, int n_in,
                              void* d_out, int out_size, void* d_ws, size_t ws_size,
                              hipStream_t stream)
{
    const float* x      = (const float*)d_in[0];
    const float* pre_W1 = (const float*)d_in[2];
    const float* pre_b1 = (const float*)d_in[3];
    const float* pre_a1 = (const float*)d_in[4];
    const float* pre_W2 = (const float*)d_in[5];
    const float* pre_b2 = (const float*)d_in[6];
    const float* pre_a2 = (const float*)d_in[7];
    const float* bn_g   = (const float*)d_in[8];
    const float* bn_b   = (const float*)d_in[9];
    const float* act_a  = (const float*)d_in[10];
    const float* conv_Wm= (const float*)d_in[11];
    const float* conv_bm= (const float*)d_in[12];
    const float* hlv_W1 = (const float*)d_in[13];
    const float* hlv_b1 = (const float*)d_in[14];
    const float* hlv_W2 = (const float*)d_in[15];
    const float* hlv_b2 = (const float*)d_in[16];

    char* ws = (char*)d_ws;
    int*   knn     = (int*)ws;                                  // 3 MB
    float* bn_part = (float*)(ws + (size_t)6*NN*sizeof(int));   // 8 KB

    scan_kernel<<<GG*4, PP, 0, stream>>>(x, pre_W1,pre_b1,pre_a1,
                                         pre_W2,pre_b2,pre_a2, bn_part, knn);
    graph_kernel<<<GG, PP, 0, stream>>>(x, knn, bn_part,
                                        pre_W1,pre_b1,pre_a1, pre_W2,pre_b2,pre_a2,
                                        bn_g,bn_b, act_a, conv_Wm,conv_bm,
                                        hlv_W1,hlv_b1,hlv_W2,hlv_b2,
                                        (float*)d_out);
}